// Round 1
// baseline (1355.468 us; speedup 1.0000x reference)
//
#include <hip/hip_runtime.h>
#include <math.h>
#include <stddef.h>

#define NLAYER 24
#define NEMBD  1024
#define NFFN   4096
#define NB     256
#define NT     256
#define NW     (NT/64)
#define LN_EPS 1e-5f

#define OUT_SA (NEMBD)
#define OUT_SB (NEMBD + NLAYER*NEMBD)
#define OUT_SC (NEMBD + 2*NLAYER*NEMBD)
#define OUT_SD (NEMBD + 3*NLAYER*NEMBD)

struct Params {
  const float *x, *state, *ln1w, *ln1b, *ln2w, *ln2b, *td, *tf, *kktk, *vvtv, *rrtr;
  const float *key, *outputv, *tmk, *tmr, *kffn, *rffn, *vffn;
  float *out;
  float *xbuf, *kvr, *sxx, *rfb, *kfb;
  unsigned *cnt, *gen;
};

__device__ __forceinline__ float wred(float v) {
#pragma unroll
  for (int o = 32; o > 0; o >>= 1) v += __shfl_xor(v, o, 64);
  return v;
}

__device__ __forceinline__ float dot4(float4 a, float4 b) {
  return a.x*b.x + a.y*b.y + a.z*b.z + a.w*b.w;
}

// Monotonic-count grid barrier. cnt/gen zeroed by init kernel each call.
// Release: __syncthreads drains each wave's vmem (vmcnt 0), then thread 0's
// __threadfence writes back the XCD L2 so data is visible at the LLC.
// Acquire: after observing the generation flag, __threadfence invalidates
// L1/L2 so subsequent reads see other XCDs' writes.
__device__ __forceinline__ void gbar(unsigned* cnt, unsigned* gen, unsigned g) {
  __syncthreads();
  if (threadIdx.x == 0) {
    __threadfence();
    unsigned a = __hip_atomic_fetch_add(cnt, 1u, __ATOMIC_RELAXED, __HIP_MEMORY_SCOPE_AGENT);
    if (a == (g + 1u) * (unsigned)NB - 1u) {
      __hip_atomic_store(gen, g + 1u, __ATOMIC_RELAXED, __HIP_MEMORY_SCOPE_AGENT);
    } else {
      long spin = 0;
      while (__hip_atomic_load(gen, __ATOMIC_RELAXED, __HIP_MEMORY_SCOPE_AGENT) <= g) {
        __builtin_amdgcn_s_sleep(1);
        if (++spin > (1L << 28)) break;  // safety valve: wrong answer beats a hang
      }
    }
    __threadfence();
  }
  __syncthreads();
}

__global__ void __launch_bounds__(NT)
rwkv_persistent(Params p) {
  const int b    = blockIdx.x;
  const int t    = threadIdx.x;
  const int wid  = t >> 6;
  const int lane = t & 63;

  __shared__ float lds[NFFN];           // 16 KiB, reused per stage
  __shared__ float reda[NW], redq[NW];
  __shared__ float mrs[2];

  unsigned g = 0;

  // ---- stage -1: stage x into ws ----
  if (b == 0) {
    *(float4*)&p.xbuf[t * 4] = *(const float4*)&p.x[t * 4];
  }
  gbar(p.cnt, p.gen, g); ++g;

  for (int l = 0; l < NLAYER; ++l) {
    // ================= stage 1: ln1 + k/v/r GEMV =================
    {
      const int i0 = t * 4;
      float4 x4 = *(const float4*)&p.xbuf[i0];
      float xa[4] = {x4.x, x4.y, x4.z, x4.w};
      float s = xa[0] + xa[1] + xa[2] + xa[3];
      float q = xa[0]*xa[0] + xa[1]*xa[1] + xa[2]*xa[2] + xa[3]*xa[3];
      s = wred(s); q = wred(q);
      if (lane == 0) { reda[wid] = s; redq[wid] = q; }
      __syncthreads();
      if (t == 0) {
        float ts = 0.f, tq = 0.f;
#pragma unroll
        for (int i = 0; i < NW; ++i) { ts += reda[i]; tq += redq[i]; }
        float m = ts * (1.f / NEMBD);
        float var = tq * (1.f / NEMBD) - m * m;
        mrs[0] = m; mrs[1] = rsqrtf(var + LN_EPS);
      }
      __syncthreads();
      float m = mrs[0], rs = mrs[1];
      const float* l1w = p.ln1w + l * NEMBD;
      const float* l1b = p.ln1b + l * NEMBD;
      const float* sa  = p.state + 0 * NLAYER * NEMBD + l * NEMBD;
      const float* kkp = p.kktk + l * NEMBD;
      const float* vvp = p.vvtv + l * NEMBD;
      const float* rrp = p.rrtr + l * NEMBD;
#pragma unroll
      for (int j = 0; j < 4; ++j) {
        int i = i0 + j;
        float xy = (xa[j] - m) * rs * l1w[i] + l1b[i];
        float sav = sa[i];
        lds[i]             = xy + kkp[i] * sav;
        lds[NEMBD + i]     = xy + vvp[i] * sav;
        lds[2 * NEMBD + i] = xy + rrp[i] * sav;
        if (b == 0) p.out[OUT_SA + l * NEMBD + i] = xy;   // statea_new = xy
      }
      __syncthreads();

      const float* W = p.key + (size_t)l * 3 * NEMBD * NEMBD;
      const int r0 = b * 12 + wid * 3;   // 3072 rows over 1024 waves
      const float* v0 = lds + ((r0 + 0) >> 10) * NEMBD;
      const float* v1 = lds + ((r0 + 1) >> 10) * NEMBD;
      const float* v2 = lds + ((r0 + 2) >> 10) * NEMBD;
      const float* w0 = W + (size_t)(r0 + 0) * NEMBD;
      const float* w1 = W + (size_t)(r0 + 1) * NEMBD;
      const float* w2 = W + (size_t)(r0 + 2) * NEMBD;
      float acc0 = 0.f, acc1 = 0.f, acc2 = 0.f;
#pragma unroll
      for (int jj = 0; jj < 4; ++jj) {
        int col = lane * 4 + jj * 256;
        float4 a0 = *(const float4*)&w0[col];
        float4 a1 = *(const float4*)&w1[col];
        float4 a2 = *(const float4*)&w2[col];
        float4 b0 = *(const float4*)&v0[col];
        float4 b1 = *(const float4*)&v1[col];
        float4 b2 = *(const float4*)&v2[col];
        acc0 += dot4(a0, b0);
        acc1 += dot4(a1, b1);
        acc2 += dot4(a2, b2);
      }
      acc0 = wred(acc0); acc1 = wred(acc1); acc2 = wred(acc2);
      if (lane == 0) {
        p.kvr[r0 + 0] = acc0;
        p.kvr[r0 + 1] = acc1;
        p.kvr[r0 + 2] = acc2;
      }
    }
    gbar(p.cnt, p.gen, g); ++g;

    // ================= stage 2: wkv combine + outputv GEMV + state out ====
    {
      const int i0 = t * 4;
      const float* tfp = p.tf + l * NEMBD;
      const float* sbp = p.state + 1 * NLAYER * NEMBD + l * NEMBD;
      const float* scp = p.state + 2 * NLAYER * NEMBD + l * NEMBD;
      const float* tdp = p.td + l * NEMBD;
#pragma unroll
      for (int j = 0; j < 4; ++j) {
        int i = i0 + j;
        float k = p.kvr[i];
        float v = p.kvr[NEMBD + i];
        float r = p.kvr[2 * NEMBD + i];
        float sb = sbp[i], sc = scp[i];
        float etfk = expf(tfp[i] + k);
        float er   = expf(r);
        // sc*er + exp(tf+k+r) + sc + etfk == (sc+etfk)*(1+er)
        lds[i] = (sb + etfk * v) / ((sc + etfk) * (1.f + er));
        if (b == 0) {
          float ek = expf(k), ed = expf(tdp[i]);
          p.out[OUT_SB + l * NEMBD + i] = sb * ed + ek * v;
          p.out[OUT_SC + l * NEMBD + i] = sc * ed + ek;
        }
      }
      __syncthreads();
      const int row = b * 4 + wid;       // 1024 rows, 1 per wave
      const float* W = p.outputv + ((size_t)l * NEMBD + row) * NEMBD;
      float acc = 0.f;
#pragma unroll
      for (int jj = 0; jj < 4; ++jj) {
        int col = lane * 4 + jj * 256;
        acc += dot4(*(const float4*)&W[col], *(const float4*)&lds[col]);
      }
      acc = wred(acc);
      if (lane == 0) p.sxx[row] = p.xbuf[row] + acc;
    }
    gbar(p.cnt, p.gen, g); ++g;

    // ================= stage 3: ln2 + key_ffn / receptance_ffn GEMV =======
    {
      const int i0 = t * 4;
      float4 s4 = *(const float4*)&p.sxx[i0];
      float xa[4] = {s4.x, s4.y, s4.z, s4.w};
      float s = xa[0] + xa[1] + xa[2] + xa[3];
      float q = xa[0]*xa[0] + xa[1]*xa[1] + xa[2]*xa[2] + xa[3]*xa[3];
      s = wred(s); q = wred(q);
      if (lane == 0) { reda[wid] = s; redq[wid] = q; }
      __syncthreads();
      if (t == 0) {
        float ts = 0.f, tq = 0.f;
#pragma unroll
        for (int i = 0; i < NW; ++i) { ts += reda[i]; tq += redq[i]; }
        float m = ts * (1.f / NEMBD);
        float var = tq * (1.f / NEMBD) - m * m;
        mrs[0] = m; mrs[1] = rsqrtf(var + LN_EPS);
      }
      __syncthreads();
      float m = mrs[0], rs = mrs[1];
      const float* l2w = p.ln2w + l * NEMBD;
      const float* l2b = p.ln2b + l * NEMBD;
      const float* sdp = p.state + 3 * NLAYER * NEMBD + l * NEMBD;
      const float* tmkp = p.tmk + l * NEMBD;
      const float* tmrp = p.tmr + l * NEMBD;
#pragma unroll
      for (int j = 0; j < 4; ++j) {
        int i = i0 + j;
        float xx = (xa[j] - m) * rs * l2w[i] + l2b[i];
        float sdv = sdp[i];
        lds[i]         = xx + tmkp[i] * sdv;
        lds[NEMBD + i] = xx + tmrp[i] * sdv;
        if (b == 0) p.out[OUT_SD + l * NEMBD + i] = xx;   // stated_new = xx
      }
      __syncthreads();

      // 20 rows/block: 16 key_ffn rows + 4 receptance_ffn rows; 5 per wave
      const float* wp[5]; const float* vp[5]; int isk[5]; int rowid[5];
#pragma unroll
      for (int sI = 0; sI < 5; ++sI) {
        int qI = wid * 5 + sI;
        if (qI < 16) {
          int row = b * 16 + qI;
          wp[sI] = p.kffn + ((size_t)l * NFFN + row) * NEMBD;
          vp[sI] = lds;
          isk[sI] = 1; rowid[sI] = row;
        } else {
          int row = b * 4 + (qI - 16);
          wp[sI] = p.rffn + ((size_t)l * NEMBD + row) * NEMBD;
          vp[sI] = lds + NEMBD;
          isk[sI] = 0; rowid[sI] = row;
        }
      }
      float acc[5] = {0.f, 0.f, 0.f, 0.f, 0.f};
#pragma unroll
      for (int jj = 0; jj < 4; ++jj) {
        int col = lane * 4 + jj * 256;
#pragma unroll
        for (int sI = 0; sI < 5; ++sI) {
          acc[sI] += dot4(*(const float4*)&wp[sI][col], *(const float4*)&vp[sI][col]);
        }
      }
#pragma unroll
      for (int sI = 0; sI < 5; ++sI) {
        float r = wred(acc[sI]);
        if (lane == 0) {
          if (isk[sI]) { float kv = fmaxf(r, 0.f); p.kfb[rowid[sI]] = kv * kv; }
          else         { p.rfb[rowid[sI]] = expf(r); }
        }
      }
    }
    gbar(p.cnt, p.gen, g); ++g;

    // ================= stage 4: value_ffn GEMV + x update =================
    {
#pragma unroll
      for (int pass = 0; pass < 4; ++pass) {
        int idx = pass * NEMBD + t * 4;
        *(float4*)&lds[idx] = *(const float4*)&p.kfb[idx];
      }
      __syncthreads();
      const int row = b * 4 + wid;       // 1024 rows, 1 per wave, len 4096
      const float* W = p.vffn + ((size_t)l * NEMBD + row) * NFFN;
      float accA = 0.f, accB = 0.f;
#pragma unroll
      for (int jj = 0; jj < 16; jj += 2) {
        int col = lane * 4 + jj * 256;
        float4 a0 = *(const float4*)&W[col];
        float4 b0 = *(const float4*)&lds[col];
        float4 a1 = *(const float4*)&W[col + 256];
        float4 b1 = *(const float4*)&lds[col + 256];
        accA += dot4(a0, b0);
        accB += dot4(a1, b1);
      }
      float acc = wred(accA + accB);
      if (lane == 0) {
        float xn = p.sxx[row] + acc / (p.rfb[row] + 1.f);
        if (l == NLAYER - 1) p.out[row] = xn;     // final x_out
        else                 p.xbuf[row] = xn;
      }
    }
    gbar(p.cnt, p.gen, g); ++g;
  }
}

__global__ void rwkv_init(unsigned* cnt, unsigned* gen) {
  *cnt = 0u;
  *gen = 0u;
}

extern "C" void kernel_launch(void* const* d_in, const int* in_sizes, int n_in,
                              void* d_out, int out_size, void* d_ws, size_t ws_size,
                              hipStream_t stream) {
  Params p;
  p.x       = (const float*)d_in[0];
  p.state   = (const float*)d_in[1];
  p.ln1w    = (const float*)d_in[2];
  p.ln1b    = (const float*)d_in[3];
  p.ln2w    = (const float*)d_in[4];
  p.ln2b    = (const float*)d_in[5];
  p.td      = (const float*)d_in[6];
  p.tf      = (const float*)d_in[7];
  p.kktk    = (const float*)d_in[8];
  p.vvtv    = (const float*)d_in[9];
  p.rrtr    = (const float*)d_in[10];
  p.key     = (const float*)d_in[11];
  p.outputv = (const float*)d_in[12];
  p.tmk     = (const float*)d_in[13];
  p.tmr     = (const float*)d_in[14];
  p.kffn    = (const float*)d_in[15];
  p.rffn    = (const float*)d_in[16];
  p.vffn    = (const float*)d_in[17];
  p.out     = (float*)d_out;

  float* ws = (float*)d_ws;
  p.xbuf = ws;                       // [1024]
  p.kvr  = ws + NEMBD;               // [3*1024]
  p.sxx  = ws + 4 * NEMBD;           // [1024]
  p.rfb  = ws + 5 * NEMBD;           // [1024]
  p.kfb  = ws + 6 * NEMBD;           // [4096]  (ends at float 10240 = byte 40960)
  p.cnt  = (unsigned*)((char*)d_ws + 41088);
  p.gen  = (unsigned*)((char*)d_ws + 41216);

  rwkv_init<<<1, 1, 0, stream>>>(p.cnt, p.gen);
  rwkv_persistent<<<NB, NT, 0, stream>>>(p);
}